// Round 1
// baseline (200.011 us; speedup 1.0000x reference)
//
#include <hip/hip_runtime.h>
#include <math.h>

#define N_DIM 4
#define C_DIM 4096
#define EPSF 1e-6f

// One block per batch row b. 256 threads; each thread owns 4 float4 chunks
// (16 c-values) per stream n -> whole 4x4096 row lives in registers.
__global__ __launch_bounds__(256) void mhc_fused_kernel(
    const float* __restrict__ x,      // [B, 4, 4096]
    const float* __restrict__ H_pre,  // [4]
    const float* __restrict__ H_post, // [4]
    const float* __restrict__ H_res,  // [4,4]
    const float* __restrict__ w,      // [4096]
    float* __restrict__ out)          // [B, 4, 4096]
{
    __shared__ float sP[16];
    __shared__ float sPre[4];
    __shared__ float sPost[4];
    __shared__ float sRed[4];

    const int b = blockIdx.x;
    const int t = threadIdx.x;

    // ---- issue global loads early (latency overlaps sinkhorn) ----
    const float4* x4 = reinterpret_cast<const float4*>(x + (size_t)b * (N_DIM * C_DIM));
    const float4* w4 = reinterpret_cast<const float4*>(w);

    float4 xv[4][4];   // [i-chunk][stream n]
#pragma unroll
    for (int i = 0; i < 4; ++i)
#pragma unroll
        for (int n = 0; n < 4; ++n)
            xv[i][n] = x4[n * (C_DIM / 4) + i * 256 + t];

    float4 wv[4];
#pragma unroll
    for (int i = 0; i < 4; ++i)
        wv[i] = w4[i * 256 + t];

    // ---- thread 0: gates + sinkhorn (tiny 4x4) ----
    if (t == 0) {
        float P[4][4];
#pragma unroll
        for (int i = 0; i < 4; ++i)
#pragma unroll
            for (int j = 0; j < 4; ++j)
                P[i][j] = expf(H_res[i * 4 + j]);
#pragma unroll
        for (int it = 0; it < 3; ++it) {
            // row normalize (sum over last axis)
#pragma unroll
            for (int i = 0; i < 4; ++i) {
                float s = P[i][0] + P[i][1] + P[i][2] + P[i][3] + EPSF;
#pragma unroll
                for (int j = 0; j < 4; ++j) P[i][j] /= s;
            }
            // column normalize (sum over axis -2)
#pragma unroll
            for (int j = 0; j < 4; ++j) {
                float s = P[0][j] + P[1][j] + P[2][j] + P[3][j] + EPSF;
#pragma unroll
                for (int i = 0; i < 4; ++i) P[i][j] /= s;
            }
        }
#pragma unroll
        for (int i = 0; i < 4; ++i)
#pragma unroll
            for (int j = 0; j < 4; ++j)
                sP[i * 4 + j] = P[i][j];
#pragma unroll
        for (int n = 0; n < 4; ++n) {
            sPre[n]  = 1.0f / (1.0f + expf(-H_pre[n]));
            sPost[n] = 2.0f / (1.0f + expf(-H_post[n]));
        }
    }
    __syncthreads();

    float pre[4], post[4], Pm[4][4];
#pragma unroll
    for (int n = 0; n < 4; ++n) { pre[n] = sPre[n]; post[n] = sPost[n]; }
#pragma unroll
    for (int i = 0; i < 4; ++i)
#pragma unroll
        for (int j = 0; j < 4; ++j)
            Pm[i][j] = sP[i * 4 + j];

    // ---- gated aggregate + sum of squares ----
    float4 agg[4];
    float ssq = 0.0f;
#pragma unroll
    for (int i = 0; i < 4; ++i) {
        float4 a;
        a.x = pre[0] * xv[i][0].x + pre[1] * xv[i][1].x + pre[2] * xv[i][2].x + pre[3] * xv[i][3].x;
        a.y = pre[0] * xv[i][0].y + pre[1] * xv[i][1].y + pre[2] * xv[i][2].y + pre[3] * xv[i][3].y;
        a.z = pre[0] * xv[i][0].z + pre[1] * xv[i][1].z + pre[2] * xv[i][2].z + pre[3] * xv[i][3].z;
        a.w = pre[0] * xv[i][0].w + pre[1] * xv[i][1].w + pre[2] * xv[i][2].w + pre[3] * xv[i][3].w;
        agg[i] = a;
        ssq += a.x * a.x + a.y * a.y + a.z * a.z + a.w * a.w;
    }

    // ---- block reduction of ssq over 4096 c-values ----
#pragma unroll
    for (int off = 32; off > 0; off >>= 1)
        ssq += __shfl_down(ssq, off);
    if ((t & 63) == 0) sRed[t >> 6] = ssq;
    __syncthreads();
    float tot = sRed[0] + sRed[1] + sRed[2] + sRed[3];
    float inv_rms = rsqrtf(tot * (1.0f / (float)C_DIM) + EPSF);

    // ---- mix streams + add post-gated RMS-normed aggregate; store ----
    float4* o4 = reinterpret_cast<float4*>(out + (size_t)b * (N_DIM * C_DIM));
#pragma unroll
    for (int m = 0; m < 4; ++m) {
        const float p0 = Pm[m][0], p1 = Pm[m][1], p2 = Pm[m][2], p3 = Pm[m][3];
        const float pg = post[m];
#pragma unroll
        for (int i = 0; i < 4; ++i) {
            float4 o;
            o.x = p0 * xv[i][0].x + p1 * xv[i][1].x + p2 * xv[i][2].x + p3 * xv[i][3].x
                + pg * (agg[i].x * inv_rms * wv[i].x);
            o.y = p0 * xv[i][0].y + p1 * xv[i][1].y + p2 * xv[i][2].y + p3 * xv[i][3].y
                + pg * (agg[i].y * inv_rms * wv[i].y);
            o.z = p0 * xv[i][0].z + p1 * xv[i][1].z + p2 * xv[i][2].z + p3 * xv[i][3].z
                + pg * (agg[i].z * inv_rms * wv[i].z);
            o.w = p0 * xv[i][0].w + p1 * xv[i][1].w + p2 * xv[i][2].w + p3 * xv[i][3].w
                + pg * (agg[i].w * inv_rms * wv[i].w);
            o4[m * (C_DIM / 4) + i * 256 + t] = o;
        }
    }
}

extern "C" void kernel_launch(void* const* d_in, const int* in_sizes, int n_in,
                              void* d_out, int out_size, void* d_ws, size_t ws_size,
                              hipStream_t stream) {
    const float* x      = (const float*)d_in[0];
    const float* H_pre  = (const float*)d_in[1];
    const float* H_post = (const float*)d_in[2];
    const float* H_res  = (const float*)d_in[3];
    const float* w      = (const float*)d_in[4];
    float* out = (float*)d_out;

    const int B = in_sizes[0] / (N_DIM * C_DIM);
    hipLaunchKernelGGL(mhc_fused_kernel, dim3(B), dim3(256), 0, stream,
                       x, H_pre, H_post, H_res, w, out);
}

// Round 3
// 187.561 us; speedup vs baseline: 1.0664x; 1.0664x over previous
//
#include <hip/hip_runtime.h>
#include <math.h>

#define N_DIM 4
#define C_DIM 4096
#define EPSF 1e-6f
#define TPB 512
#define CHUNKS 2   // (C_DIM/4) float4 per stream / TPB threads

typedef float f32x4 __attribute__((ext_vector_type(4)));

// One block per batch row b. 512 threads; each thread owns 2 float4 chunks
// (8 c-values) per stream n -> whole 4x4096 fp32 row lives in block registers.
__global__ __launch_bounds__(TPB) void mhc_fused_kernel(
    const float* __restrict__ x,      // [B, 4, 4096]
    const float* __restrict__ H_pre,  // [4]
    const float* __restrict__ H_post, // [4]
    const float* __restrict__ H_res,  // [4,4]
    const float* __restrict__ w,      // [4096]
    float* __restrict__ out)          // [B, 4, 4096]
{
    __shared__ float sRed[TPB / 64];

    const int b = blockIdx.x;
    const int t = threadIdx.x;

    const f32x4* x4 = reinterpret_cast<const f32x4*>(x + (size_t)b * (N_DIM * C_DIM));
    const f32x4* w4 = reinterpret_cast<const f32x4*>(w);

    // ---- issue streaming loads first (latency hides the scalar math below) ----
    f32x4 xv[CHUNKS][4];   // [chunk][stream n]
#pragma unroll
    for (int i = 0; i < CHUNKS; ++i)
#pragma unroll
        for (int n = 0; n < 4; ++n)
            xv[i][n] = __builtin_nontemporal_load(&x4[n * (C_DIM / 4) + i * TPB + t]);

    f32x4 wv[CHUNKS];      // w is reused by every block -> temporal (cached) load
#pragma unroll
    for (int i = 0; i < CHUNKS; ++i)
        wv[i] = w4[i * TPB + t];

    // ---- gates + sinkhorn, computed redundantly by every thread (uniform) ----
    float pre[4], post[4], P[4][4];
#pragma unroll
    for (int n = 0; n < 4; ++n) {
        pre[n]  = 1.0f / (1.0f + expf(-H_pre[n]));
        post[n] = 2.0f / (1.0f + expf(-H_post[n]));
    }
#pragma unroll
    for (int i = 0; i < 4; ++i)
#pragma unroll
        for (int j = 0; j < 4; ++j)
            P[i][j] = expf(H_res[i * 4 + j]);
#pragma unroll
    for (int it = 0; it < 3; ++it) {
#pragma unroll
        for (int i = 0; i < 4; ++i) {           // row normalize (sum over axis -1)
            float s = P[i][0] + P[i][1] + P[i][2] + P[i][3] + EPSF;
            float r = 1.0f / s;
#pragma unroll
            for (int j = 0; j < 4; ++j) P[i][j] *= r;
        }
#pragma unroll
        for (int j = 0; j < 4; ++j) {           // column normalize (sum over axis -2)
            float s = P[0][j] + P[1][j] + P[2][j] + P[3][j] + EPSF;
            float r = 1.0f / s;
#pragma unroll
            for (int i = 0; i < 4; ++i) P[i][j] *= r;
        }
    }

    // ---- gated aggregate + local sum of squares ----
    f32x4 agg[CHUNKS];
    float ssq = 0.0f;
#pragma unroll
    for (int i = 0; i < CHUNKS; ++i) {
        f32x4 a = pre[0] * xv[i][0] + pre[1] * xv[i][1] + pre[2] * xv[i][2] + pre[3] * xv[i][3];
        agg[i] = a;
        ssq += a.x * a.x + a.y * a.y + a.z * a.z + a.w * a.w;
    }

    // ---- block reduction of ssq over the 4096 c-values (8 waves) ----
#pragma unroll
    for (int off = 32; off > 0; off >>= 1)
        ssq += __shfl_down(ssq, off);
    if ((t & 63) == 0) sRed[t >> 6] = ssq;
    __syncthreads();
    float tot = 0.0f;
#pragma unroll
    for (int k = 0; k < TPB / 64; ++k) tot += sRed[k];
    float inv_rms = rsqrtf(tot * (1.0f / (float)C_DIM) + EPSF);

    // ---- mix streams + post-gated RMS-normed aggregate; streaming store ----
    f32x4* o4 = reinterpret_cast<f32x4*>(out + (size_t)b * (N_DIM * C_DIM));
#pragma unroll
    for (int m = 0; m < 4; ++m) {
        const float p0 = P[m][0], p1 = P[m][1], p2 = P[m][2], p3 = P[m][3];
        const float pg = post[m];
#pragma unroll
        for (int i = 0; i < CHUNKS; ++i) {
            f32x4 o = p0 * xv[i][0] + p1 * xv[i][1] + p2 * xv[i][2] + p3 * xv[i][3]
                    + (pg * inv_rms) * (agg[i] * wv[i]);
            __builtin_nontemporal_store(o, &o4[m * (C_DIM / 4) + i * TPB + t]);
        }
    }
}

extern "C" void kernel_launch(void* const* d_in, const int* in_sizes, int n_in,
                              void* d_out, int out_size, void* d_ws, size_t ws_size,
                              hipStream_t stream) {
    const float* x      = (const float*)d_in[0];
    const float* H_pre  = (const float*)d_in[1];
    const float* H_post = (const float*)d_in[2];
    const float* H_res  = (const float*)d_in[3];
    const float* w      = (const float*)d_in[4];
    float* out = (float*)d_out;

    const int B = in_sizes[0] / (N_DIM * C_DIM);
    hipLaunchKernelGGL(mhc_fused_kernel, dim3(B), dim3(TPB), 0, stream,
                       x, H_pre, H_post, H_res, w, out);
}